// Round 4
// baseline (1102.700 us; speedup 1.0000x reference)
//
#include <hip/hip_runtime.h>
#include <math.h>

// B=8, N=40962, D=40, H=512, D_DYN=32, 4 steps, dt=0.1
constexpr int BB   = 8;
constexpr int NN   = 40962;
constexpr int DDIM = 40;
constexpr int HH   = 512;
constexpr int DDYN = 32;
constexpr float STEPSZ = 0.1f;

constexpr int TM   = 64;      // nodes per block
constexpr int NTHR = 512;     // 8 waves
constexpr int ZS   = 168;     // z LDS row stride (bf16): 336B = 21*16B, 2-way banks = free
constexpr int FZS  = 36;      // fz LDS row stride (f32): 144B breaks the *128B pattern

constexpr size_t X_ELEMS = (size_t)BB * NN * DDIM;
constexpr size_t X_BYTES = X_ELEMS * 4;
constexpr int W1P_ELEMS = 32 * 5 * 64 * 8;   // [mt][kk][lane][j] A-frags
constexpr int W2P_ELEMS = 2 * 16 * 64 * 8;   // [jt][kk][lane][j] A-frags

// LDS budget: z 64*168*2 = 21504 | hh 64*256*2 = 32768 | total 54272 <= 163840/3
constexpr int Z_BYTES  = TM * ZS * 2;
constexpr int HH_BYTES = TM * 256 * 2;

typedef __attribute__((ext_vector_type(8))) short short8;
typedef __attribute__((ext_vector_type(4))) float f32x4;
typedef __attribute__((ext_vector_type(4))) unsigned short u16x4;

__device__ __forceinline__ unsigned short bf16_rne(float f) {
    unsigned int u = __float_as_uint(f);
    unsigned int r = (u + 0x7FFFu + ((u >> 16) & 1u)) >> 16;
    return (unsigned short)r;
}

__device__ __forceinline__ unsigned int pk_bf16(float a, float b) {
#if __has_builtin(__builtin_amdgcn_cvt_pk_bf16_f32)
    auto v = __builtin_amdgcn_cvt_pk_bf16_f32(a, b);
    unsigned int r;
    __builtin_memcpy(&r, &v, 4);
    return r;
#else
    return (unsigned int)bf16_rne(a) | ((unsigned int)bf16_rne(b) << 16);
#endif
}

__device__ __forceinline__ float gelu_fast(float x) {
    // 0.5x(1+tanh(c(x+0.044715x^3))) == x * sigmoid(2c(x+0.044715x^3))
    float u = x * fmaf(0.044715f, x * x, 1.0f);
    float e = __expf(-1.5957691216057308f * u);
    return x * __builtin_amdgcn_rcpf(1.0f + e);
}

// ---- A-position fragment packing (same as round 3, verified) ----
__global__ __launch_bounds__(256) void pack_w1(const float* __restrict__ W1,
                                               unsigned short* __restrict__ W1p) {
    int t = blockIdx.x * 256 + threadIdx.x;
    if (t >= W1P_ELEMS) return;
    int j = t & 7, ln = (t >> 3) & 63, g = t >> 9;
    int kk = g % 5, mt = g / 5;
    int nl = ln & 15, q = ln >> 4;
    int k = kk * 32 + q * 8 + j, m = mt * 16 + nl;
    W1p[t] = bf16_rne(W1[(size_t)k * HH + m]);
}
__global__ __launch_bounds__(256) void pack_w2(const float* __restrict__ W2,
                                               unsigned short* __restrict__ W2p) {
    int t = blockIdx.x * 256 + threadIdx.x;
    if (t >= W2P_ELEMS) return;
    int j = t & 7, ln = (t >> 3) & 63, g = t >> 9;
    int kk = g & 15, jt = g >> 4;
    int nl = ln & 15, q = ln >> 4;
    int k = kk * 32 + q * 8 + j, m = jt * 16 + nl;
    W2p[t] = bf16_rne(W2[(size_t)k * DDYN + m]);
}

// hh (half of h): [64 nodes][256 cols] bf16, XOR-swizzled 16B chunks:
// elem(node,c) = node*256 + (((c>>3) ^ (node&7))<<3) + (c&7)
__global__ __launch_bounds__(NTHR, 6) void step_mfma(
    const float* __restrict__ xsrc, float* __restrict__ xdst,
    const int* __restrict__ index,
    const unsigned short* __restrict__ W1p, const float* __restrict__ b1,
    const unsigned short* __restrict__ W2p, const float* __restrict__ b2)
{
    __shared__ alignas(16) unsigned char smem[Z_BYTES + HH_BYTES];  // 54272 B
    unsigned short* z  = (unsigned short*)smem;              // [64][ZS], live through half B
    unsigned short* hh = (unsigned short*)(smem + Z_BYTES);  // [64][256] swizzled
    float* fz          = (float*)smem;                       // [64][FZS] overlay (z dead)

    const int tid = threadIdx.x;
    const int w   = tid >> 6;
    const int ln  = tid & 63;
    const int nl  = ln & 15;
    const int q   = ln >> 4;
    const int n0  = blockIdx.x * TM;
    const int b   = blockIdx.y;
    const size_t xbase = (size_t)b * NN * DDIM;

    // ---- Phase 1: gather -> z (bf16) ----
    for (int e = tid; e < TM * 4 * 10; e += NTHR) {
        int m = e / 40, r = e - m * 40;
        int k = r / 10, qq = r - k * 10;
        u16x4 out = (u16x4)0;
        int n = n0 + m;
        if (n < NN) {
            int nb = index[n * 4 + k];
            const float4* src = (const float4*)(xsrc + xbase + (size_t)nb * DDIM);
            float4 v = src[qq];
            out.x = bf16_rne(v.x); out.y = bf16_rne(v.y);
            out.z = bf16_rne(v.z); out.w = bf16_rne(v.w);
        }
        *(u16x4*)(z + m * ZS + k * 40 + qq * 4) = out;
    }
    __syncthreads();

    // GEMM2 accumulator (bias once), wave task: jt = w>>2, node tile nt2 = w&3
    const int jt = w >> 2, nt2 = w & 3;
    const int hrow = nt2 * 16 + nl;
    f32x4 acc2;
    {
        float4 bv = *(const float4*)(b2 + jt * 16 + q * 4);
        acc2[0] = bv.x; acc2[1] = bv.y; acc2[2] = bv.z; acc2[3] = bv.w;
    }

    #pragma unroll
    for (int half = 0; half < 2; ++half) {
        if (half) __syncthreads();   // all GEMM2 reads of hh (half A) done

        // ---- GEMM1 (half): hid tiles mtb, mtb+1 ----
        const int mtb = half * 16 + w * 2;
        f32x4 acc[2][4];
        #pragma unroll
        for (int i = 0; i < 2; ++i) {
            float4 bv = *(const float4*)(b1 + (mtb + i) * 16 + q * 4);
            f32x4 a; a[0] = bv.x; a[1] = bv.y; a[2] = bv.z; a[3] = bv.w;
            #pragma unroll
            for (int nt = 0; nt < 4; ++nt) acc[i][nt] = a;
        }
        #pragma unroll
        for (int kk = 0; kk < 5; ++kk) {
            short8 bfr[4];
            #pragma unroll
            for (int nt = 0; nt < 4; ++nt)
                bfr[nt] = *(const short8*)(z + (nt * 16 + nl) * ZS + kk * 32 + q * 8);
            #pragma unroll
            for (int i = 0; i < 2; ++i) {
                short8 afr = *(const short8*)(W1p + (size_t)(((mtb + i) * 5 + kk) * 512 + ln * 8));
                #pragma unroll
                for (int nt = 0; nt < 4; ++nt)
                    acc[i][nt] = __builtin_amdgcn_mfma_f32_16x16x32_bf16(afr, bfr[nt], acc[i][nt], 0, 0, 0);
            }
        }

        // ---- gelu -> hh (half-local hid hl = (w*2+i)*16 + q*4) ----
        #pragma unroll
        for (int i = 0; i < 2; ++i) {
            const int hl = (w * 2 + i) * 16 + q * 4;
            const int chunk = hl >> 3;
            #pragma unroll
            for (int nt = 0; nt < 4; ++nt) {
                f32x4 a = acc[i][nt];
                unsigned int p0 = pk_bf16(gelu_fast(a[0]), gelu_fast(a[1]));
                unsigned int p1 = pk_bf16(gelu_fast(a[2]), gelu_fast(a[3]));
                int node = nt * 16 + nl;
                uint2 val; val.x = p0; val.y = p1;
                *(uint2*)(hh + node * 256 + ((chunk ^ (node & 7)) << 3) + (hl & 7)) = val;
            }
        }
        __syncthreads();

        // ---- GEMM2 partial: k = half*256 .. +255 ----
        #pragma unroll
        for (int kk = 0; kk < 8; ++kk) {
            int kg = half * 8 + kk;
            short8 afr = *(const short8*)(W2p + (size_t)(((jt * 16 + kg) * 64 + ln) * 8));
            int chunk = (kk * 4 + q) ^ (hrow & 7);
            short8 bfr = *(const short8*)(hh + hrow * 256 + chunk * 8);
            acc2 = __builtin_amdgcn_mfma_f32_16x16x32_bf16(afr, bfr, acc2, 0, 0, 0);
        }
    }

    // ---- fz -> LDS (overlay z; z dead after half B's GEMM1) ----
    // lane holds fz[node=hrow][j = jt*16 + q*4 + i]
    *(f32x4*)(fz + hrow * FZS + jt * 16 + q * 4) = acc2;
    __syncthreads();

    // ---- Epilogue: full-row streaming read-modify-write ----
    for (int t = tid; t < TM * 10; t += NTHR) {
        int m = t / 10, p = t - m * 10;
        int n = n0 + m;
        if (n < NN) {
            size_t off = xbase + (size_t)n * DDIM + p * 4;
            float4 v = *(const float4*)(xsrc + off);
            if (p < 8) {
                f32x4 fv = *(const f32x4*)(fz + m * FZS + p * 4);
                v.x = fmaf(STEPSZ, fv[0], v.x);
                v.y = fmaf(STEPSZ, fv[1], v.y);
                v.z = fmaf(STEPSZ, fv[2], v.z);
                v.w = fmaf(STEPSZ, fv[3], v.w);
            }
            *(float4*)(xdst + off) = v;
        }
    }
}

// ================= fallback f32 path (used only if ws too small) =================
constexpr int FTM = 16;
__global__ __launch_bounds__(256) void step_f32(
    const float* __restrict__ xsrc, float* __restrict__ xdst,
    const int* __restrict__ index,
    const float* __restrict__ W1, const float* __restrict__ b1,
    const float* __restrict__ W2, const float* __restrict__ b2)
{
    __shared__ float z_lds[FTM][160];
    __shared__ float h_lds[FTM][HH];
    __shared__ float fz_lds[FTM][DDYN];
    const int tid = threadIdx.x, tile = blockIdx.x, b = blockIdx.y;
    const int n0 = tile * FTM;
    const int nvalid = min(FTM, NN - n0);
    for (int e = tid; e < FTM * 4 * 10; e += 256) {
        int m = e / 40, r = e % 40, k = r / 10, qq = r % 10;
        float4 v = make_float4(0.f, 0.f, 0.f, 0.f);
        int n = n0 + m;
        if (n < NN) {
            int nb = index[n * 4 + k];
            v = ((const float4*)(xsrc + ((size_t)b * NN + nb) * DDIM))[qq];
        }
        ((float4*)&z_lds[m][k * DDIM])[qq] = v;
    }
    __syncthreads();
    const int c0 = 2 * tid;
    float2 acc[FTM];
    {
        float bx = b1[c0], by = b1[c0 + 1];
        #pragma unroll
        for (int m = 0; m < FTM; ++m) { acc[m].x = bx; acc[m].y = by; }
    }
    for (int kd = 0; kd < 160; kd += 4) {
        float2 w0 = *(const float2*)(W1 + (size_t)(kd + 0) * HH + c0);
        float2 w1 = *(const float2*)(W1 + (size_t)(kd + 1) * HH + c0);
        float2 w2 = *(const float2*)(W1 + (size_t)(kd + 2) * HH + c0);
        float2 w3 = *(const float2*)(W1 + (size_t)(kd + 3) * HH + c0);
        #pragma unroll
        for (int m = 0; m < FTM; ++m) {
            float4 zv = *(const float4*)&z_lds[m][kd];
            acc[m].x = fmaf(zv.x, w0.x, acc[m].x); acc[m].y = fmaf(zv.x, w0.y, acc[m].y);
            acc[m].x = fmaf(zv.y, w1.x, acc[m].x); acc[m].y = fmaf(zv.y, w1.y, acc[m].y);
            acc[m].x = fmaf(zv.z, w2.x, acc[m].x); acc[m].y = fmaf(zv.z, w2.y, acc[m].y);
            acc[m].x = fmaf(zv.w, w3.x, acc[m].x); acc[m].y = fmaf(zv.w, w3.y, acc[m].y);
        }
    }
    #pragma unroll
    for (int m = 0; m < FTM; ++m) {
        h_lds[m][c0]     = gelu_fast(acc[m].x);
        h_lds[m][c0 + 1] = gelu_fast(acc[m].y);
    }
    __syncthreads();
    {
        const int j = tid & 31, mg = tid >> 5;
        float a0 = b2[j], a1 = a0;
        for (int c = 0; c < HH; c += 4) {
            float wa = W2[(size_t)(c + 0) * DDYN + j];
            float wb = W2[(size_t)(c + 1) * DDYN + j];
            float wc = W2[(size_t)(c + 2) * DDYN + j];
            float wd = W2[(size_t)(c + 3) * DDYN + j];
            float4 h0 = *(const float4*)&h_lds[mg][c];
            float4 h1 = *(const float4*)&h_lds[mg + 8][c];
            a0 = fmaf(h0.x, wa, a0); a0 = fmaf(h0.y, wb, a0);
            a0 = fmaf(h0.z, wc, a0); a0 = fmaf(h0.w, wd, a0);
            a1 = fmaf(h1.x, wa, a1); a1 = fmaf(h1.y, wb, a1);
            a1 = fmaf(h1.z, wc, a1); a1 = fmaf(h1.w, wd, a1);
        }
        fz_lds[mg][j] = a0; fz_lds[mg + 8][j] = a1;
    }
    __syncthreads();
    const size_t base = ((size_t)b * NN + n0) * (size_t)DDIM;
    for (int e = tid; e < nvalid * DDIM; e += 256) {
        int m = e / DDIM, d = e % DDIM;
        float v = xsrc[base + e];
        if (d < DDYN) v = fmaf(STEPSZ, fz_lds[m][d], v);
        xdst[base + e] = v;
    }
}

extern "C" void kernel_launch(void* const* d_in, const int* in_sizes, int n_in,
                              void* d_out, int out_size, void* d_ws, size_t ws_size,
                              hipStream_t stream) {
    const float* x   = (const float*)d_in[0];
    const int*   idx = (const int*)  d_in[1];
    const float* W1  = (const float*)d_in[2];
    const float* b1  = (const float*)d_in[3];
    const float* W2  = (const float*)d_in[4];
    const float* b2  = (const float*)d_in[5];
    float* out  = (float*)d_out;
    float* xbuf = (float*)d_ws;

    const size_t need = X_BYTES + (size_t)(W1P_ELEMS + W2P_ELEMS) * 2;
    if (ws_size >= need) {
        unsigned short* W1p = (unsigned short*)((char*)d_ws + X_BYTES);
        unsigned short* W2p = W1p + W1P_ELEMS;
        pack_w1<<<(W1P_ELEMS + 255) / 256, 256, 0, stream>>>(W1, W1p);
        pack_w2<<<(W2P_ELEMS + 255) / 256, 256, 0, stream>>>(W2, W2p);
        dim3 grid((NN + TM - 1) / TM, BB), block(NTHR);   // 2D grid (round-3 swizzle reverted)
        step_mfma<<<grid, block, 0, stream>>>(x,    xbuf, idx, W1p, b1, W2p, b2);
        step_mfma<<<grid, block, 0, stream>>>(xbuf, out,  idx, W1p, b1, W2p, b2);
        step_mfma<<<grid, block, 0, stream>>>(out,  xbuf, idx, W1p, b1, W2p, b2);
        step_mfma<<<grid, block, 0, stream>>>(xbuf, out,  idx, W1p, b1, W2p, b2);
    } else {
        dim3 grid((NN + FTM - 1) / FTM, BB), block(256);
        step_f32<<<grid, block, 0, stream>>>(x,    xbuf, idx, W1, b1, W2, b2);
        step_f32<<<grid, block, 0, stream>>>(xbuf, out,  idx, W1, b1, W2, b2);
        step_f32<<<grid, block, 0, stream>>>(out,  xbuf, idx, W1, b1, W2, b2);
        step_f32<<<grid, block, 0, stream>>>(xbuf, out,  idx, W1, b1, W2, b2);
    }
}

// Round 5
// 671.053 us; speedup vs baseline: 1.6432x; 1.6432x over previous
//
#include <hip/hip_runtime.h>
#include <math.h>

// B=8, N=40962, D=40, H=512, D_DYN=32, 4 steps, dt=0.1
constexpr int BB   = 8;
constexpr int NN   = 40962;
constexpr int DDIM = 40;
constexpr int HH   = 512;
constexpr int DDYN = 32;
constexpr float STEPSZ = 0.1f;

constexpr int TM   = 32;      // nodes per block
constexpr int NTHR = 512;     // 8 waves
constexpr int ZS   = 168;     // z row stride (bf16): 336B -> 2-way banks (free)

constexpr size_t X_ELEMS = (size_t)BB * NN * DDIM;
constexpr size_t X_BYTES = X_ELEMS * 4;
constexpr int W1P_ELEMS = 32 * 5 * 64 * 8;   // bf16 A-frags [mt][kk][lane][j]
constexpr int W2P_BYTES = 2 * 16 * 64 * 8;   // fp8 A-frags  [jt][kk][lane][j]

// LDS: z [32][168] bf16 = 10752 | h [32][512] fp8 = 16384 ; fz (2x 32x36 f32 = 9216) overlays z
constexpr int Z_BYTES = TM * ZS * 2;          // 10752
constexpr int H_OFF   = Z_BYTES;              // 16-aligned
constexpr int LDS_TOT = Z_BYTES + TM * HH;    // 27136

typedef __attribute__((ext_vector_type(8))) short short8;
typedef __attribute__((ext_vector_type(4))) float f32x4;
typedef __attribute__((ext_vector_type(4))) unsigned short u16x4;

__device__ __forceinline__ unsigned short bf16_rne(float f) {
    unsigned int u = __float_as_uint(f);
    return (unsigned short)((u + 0x7FFFu + ((u >> 16) & 1u)) >> 16);
}

__device__ __forceinline__ unsigned char f32_to_fp8_sw(float f) {
    if (!(f == f)) return 0x7f;
    unsigned u = __float_as_uint(f);
    unsigned s = (u >> 24) & 0x80u;
    float a = fabsf(f);
    if (a >= 464.f) return (unsigned char)(s | 0x7e);
    int e = (int)((u >> 23) & 0xff) - 127;
    if (e < -6) {
        int q = (int)fminf(fmaxf(a * 512.0f + 0.5f, 0.f), 7.f);
        return (unsigned char)(s | q);
    }
    unsigned m = u & 0x7fffffu;
    unsigned keep = m >> 20, rest = m & 0xfffffu;
    keep += (rest > 0x80000u || (rest == 0x80000u && (keep & 1u))) ? 1u : 0u;
    if (keep == 8u) { keep = 0u; ++e; if (e > 8) return (unsigned char)(s | 0x7e); }
    return (unsigned char)(s | ((unsigned)(e + 7) << 3) | keep);
}

__device__ __forceinline__ unsigned int pk4_fp8(float a, float b, float c, float d) {
#if __has_builtin(__builtin_amdgcn_cvt_pk_fp8_f32)
    int r = __builtin_amdgcn_cvt_pk_fp8_f32(a, b, 0, false);
    r     = __builtin_amdgcn_cvt_pk_fp8_f32(c, d, r, true);
    return (unsigned int)r;
#else
    return (unsigned)f32_to_fp8_sw(a) | ((unsigned)f32_to_fp8_sw(b) << 8) |
           ((unsigned)f32_to_fp8_sw(c) << 16) | ((unsigned)f32_to_fp8_sw(d) << 24);
#endif
}

__device__ __forceinline__ float gelu_fast(float x) {
    float u = x * fmaf(0.044715f, x * x, 1.0f);
    float e = __expf(-1.5957691216057308f * u);
    return x * __builtin_amdgcn_rcpf(1.0f + e);
}

// W1p bf16 A-frags: t = ((mt*5+kk)*64 + lane)*8 + j ; A[m=mt*16+nl][k=kk*32+q*8+j] = W1[k][m]
__global__ __launch_bounds__(256) void pack_w1(const float* __restrict__ W1,
                                               unsigned short* __restrict__ W1p) {
    int t = blockIdx.x * 256 + threadIdx.x;
    if (t >= W1P_ELEMS) return;
    int j = t & 7, ln = (t >> 3) & 63, g = t >> 9;
    int kk = g % 5, mt = g / 5;
    int nl = ln & 15, q = ln >> 4;
    int k = kk * 32 + q * 8 + j, m = mt * 16 + nl;
    W1p[t] = bf16_rne(W1[(size_t)k * HH + m]);
}
// W2p fp8 A-frags: t = ((jt*16+kk)*64 + lane)*8 + j ; A[m=jt*16+nl][k=kk*32+q*8+j] = W2[k][m]
__global__ __launch_bounds__(256) void pack_w2_fp8(const float* __restrict__ W2,
                                                   unsigned char* __restrict__ W2p) {
    int t = blockIdx.x * 256 + threadIdx.x;
    if (t >= W2P_BYTES) return;
    int j = t & 7, ln = (t >> 3) & 63, g = t >> 9;
    int kk = g & 15, jt = g >> 4;
    int nl = ln & 15, q = ln >> 4;
    int k = kk * 32 + q * 8 + j, m = jt * 16 + nl;
    float v = W2[(size_t)k * DDYN + m];
#if __has_builtin(__builtin_amdgcn_cvt_pk_fp8_f32)
    W2p[t] = (unsigned char)(__builtin_amdgcn_cvt_pk_fp8_f32(v, v, 0, false) & 0xff);
#else
    W2p[t] = f32_to_fp8_sw(v);
#endif
}

// h: [node(32)][hid(512)] fp8, XOR-swizzled 8B subs: byte = node*512 + ((sub8 ^ (node&7))<<3) + (hid&7)
__global__ __launch_bounds__(NTHR, 6) void step_mfma(
    const float* __restrict__ xsrc, float* __restrict__ xdst,
    const int* __restrict__ index,
    const unsigned short* __restrict__ W1p, const float* __restrict__ b1,
    const unsigned char* __restrict__ W2p, const float* __restrict__ b2)
{
    __shared__ alignas(16) unsigned char smem[LDS_TOT];
    unsigned short* z = (unsigned short*)smem;          // [32][ZS] bf16, dies after GEMM1
    unsigned char*  h = smem + H_OFF;                   // [32][512] fp8 swizzled
    float* fz0 = (float*)smem;                          // [32][36] f32 (overlay z)
    float* fz1 = (float*)(smem + TM * 36 * 4);          // [32][36] f32

    const int tid = threadIdx.x;
    const int w   = tid >> 6;
    const int ln  = tid & 63;
    const int nl  = ln & 15;
    const int q   = ln >> 4;
    const int n0  = blockIdx.x * TM;
    const int b   = blockIdx.y;
    const size_t xbase = (size_t)b * NN * DDIM;

    // ---- Phase 1: gather -> z bf16 (32 nodes x 4 nbrs x 10 float4 = 1280 tasks) ----
    for (int e = tid; e < TM * 4 * 10; e += NTHR) {
        int m = e / 40, r = e - m * 40;
        int k = r / 10, qq = r - k * 10;
        u16x4 out = (u16x4)0;
        int n = n0 + m;
        if (n < NN) {
            int nb = index[n * 4 + k];
            float4 v = ((const float4*)(xsrc + xbase + (size_t)nb * DDIM))[qq];
            out.x = bf16_rne(v.x); out.y = bf16_rne(v.y);
            out.z = bf16_rne(v.z); out.w = bf16_rne(v.w);
        }
        *(u16x4*)(z + m * ZS + k * 40 + qq * 4) = out;
    }
    __syncthreads();

    // ---- Phase 2: GEMM1  h^T = W1^T(A) . z^T(B) ; wave owns hid tiles w*4..w*4+3, 2 node tiles ----
    f32x4 acc[4][2];
    #pragma unroll
    for (int i = 0; i < 4; ++i) {
        float4 bv = *(const float4*)(b1 + (w * 4 + i) * 16 + q * 4);
        f32x4 a; a[0] = bv.x; a[1] = bv.y; a[2] = bv.z; a[3] = bv.w;
        acc[i][0] = a; acc[i][1] = a;
    }
    #pragma unroll
    for (int kk = 0; kk < 5; ++kk) {
        short8 bfr[2];
        #pragma unroll
        for (int nt = 0; nt < 2; ++nt)
            bfr[nt] = *(const short8*)(z + (nt * 16 + nl) * ZS + kk * 32 + q * 8);
        #pragma unroll
        for (int i = 0; i < 4; ++i) {
            short8 afr = *(const short8*)(W1p + (size_t)(((w * 4 + i) * 5 + kk) * 512 + ln * 8));
            #pragma unroll
            for (int nt = 0; nt < 2; ++nt)
                acc[i][nt] = __builtin_amdgcn_mfma_f32_16x16x32_bf16(afr, bfr[nt], acc[i][nt], 0, 0, 0);
        }
    }
    __syncthreads();   // all z reads done (h region is separate; barrier only orders h vs GEMM2)

    // ---- Phase 3: h = fp8(gelu(acc)) : one b32 write per (i,nt) ----
    #pragma unroll
    for (int i = 0; i < 4; ++i) {
        const int hid  = (w * 4 + i) * 16 + q * 4;
        const int sub8 = hid >> 3;          // = (w*4+i)*2 + (q>>1)
        const int o4   = (q & 1) << 2;
        #pragma unroll
        for (int nt = 0; nt < 2; ++nt) {
            f32x4 a = acc[i][nt];
            unsigned int p = pk4_fp8(gelu_fast(a[0]), gelu_fast(a[1]),
                                     gelu_fast(a[2]), gelu_fast(a[3]));
            int node = nt * 16 + nl;
            *(unsigned int*)(h + node * 512 + ((sub8 ^ (node & 7)) << 3) + o4) = p;
        }
    }
    __syncthreads();

    // ---- Phase 4: GEMM2 fz^T = W2^T(A) . h^T(B), fp8; K split across wave pairs ----
    const int kh  = w >> 2;          // K half
    const int jt  = (w >> 1) & 1;    // output j tile
    const int nt2 = w & 1;           // node tile
    const int hrow = nt2 * 16 + nl;
    f32x4 acc2;
    if (kh == 0) {
        float4 bv = *(const float4*)(b2 + jt * 16 + q * 4);
        acc2[0] = bv.x; acc2[1] = bv.y; acc2[2] = bv.z; acc2[3] = bv.w;
    } else {
        acc2[0] = acc2[1] = acc2[2] = acc2[3] = 0.f;
    }
    #pragma unroll
    for (int kk = 0; kk < 8; ++kk) {
        int kg = kh * 8 + kk;
        long long afr, bfr;
        __builtin_memcpy(&afr, W2p + (size_t)(((jt * 16 + kg) * 64 + ln) * 8), 8);
        __builtin_memcpy(&bfr, h + hrow * 512 + (((kg * 4 + q) ^ (hrow & 7)) << 3), 8);
        acc2 = __builtin_amdgcn_mfma_f32_16x16x32_fp8_fp8(afr, bfr, acc2, 0, 0, 0);
    }
    {   // partial -> fz[kh] (overlay z; z is dead)
        float* fzk = kh ? fz1 : fz0;
        *(f32x4*)(fzk + hrow * 36 + jt * 16 + q * 4) = acc2;
    }
    __syncthreads();

    // ---- Phase 5: epilogue, 32 rows x 10 float4 = 320 tasks ----
    if (tid < TM * 10) {
        int m = tid / 10, p = tid - m * 10;
        int n = n0 + m;
        if (n < NN) {
            size_t off = xbase + (size_t)n * DDIM + p * 4;
            float4 v = *(const float4*)(xsrc + off);
            if (p < 8) {
                f32x4 f0 = *(const f32x4*)(fz0 + m * 36 + p * 4);
                f32x4 f1 = *(const f32x4*)(fz1 + m * 36 + p * 4);
                v.x = fmaf(STEPSZ, f0[0] + f1[0], v.x);
                v.y = fmaf(STEPSZ, f0[1] + f1[1], v.y);
                v.z = fmaf(STEPSZ, f0[2] + f1[2], v.z);
                v.w = fmaf(STEPSZ, f0[3] + f1[3], v.w);
            }
            *(float4*)(xdst + off) = v;
        }
    }
}

// ================= fallback f32 path (used only if ws too small) =================
constexpr int FTM = 16;
__device__ __forceinline__ float gelu_f(float x) { return gelu_fast(x); }
__global__ __launch_bounds__(256) void step_f32(
    const float* __restrict__ xsrc, float* __restrict__ xdst,
    const int* __restrict__ index,
    const float* __restrict__ W1, const float* __restrict__ b1,
    const float* __restrict__ W2, const float* __restrict__ b2)
{
    __shared__ float z_lds[FTM][160];
    __shared__ float h_lds[FTM][HH];
    __shared__ float fz_lds[FTM][DDYN];
    const int tid = threadIdx.x, tile = blockIdx.x, b = blockIdx.y;
    const int n0 = tile * FTM;
    const int nvalid = min(FTM, NN - n0);
    for (int e = tid; e < FTM * 4 * 10; e += 256) {
        int m = e / 40, r = e % 40, k = r / 10, qq = r % 10;
        float4 v = make_float4(0.f, 0.f, 0.f, 0.f);
        int n = n0 + m;
        if (n < NN) {
            int nb = index[n * 4 + k];
            v = ((const float4*)(xsrc + ((size_t)b * NN + nb) * DDIM))[qq];
        }
        ((float4*)&z_lds[m][k * DDIM])[qq] = v;
    }
    __syncthreads();
    const int c0 = 2 * tid;
    float2 acc[FTM];
    {
        float bx = b1[c0], by = b1[c0 + 1];
        #pragma unroll
        for (int m = 0; m < FTM; ++m) { acc[m].x = bx; acc[m].y = by; }
    }
    for (int kd = 0; kd < 160; kd += 4) {
        float2 w0 = *(const float2*)(W1 + (size_t)(kd + 0) * HH + c0);
        float2 w1 = *(const float2*)(W1 + (size_t)(kd + 1) * HH + c0);
        float2 w2 = *(const float2*)(W1 + (size_t)(kd + 2) * HH + c0);
        float2 w3 = *(const float2*)(W1 + (size_t)(kd + 3) * HH + c0);
        #pragma unroll
        for (int m = 0; m < FTM; ++m) {
            float4 zv = *(const float4*)&z_lds[m][kd];
            acc[m].x = fmaf(zv.x, w0.x, acc[m].x); acc[m].y = fmaf(zv.x, w0.y, acc[m].y);
            acc[m].x = fmaf(zv.y, w1.x, acc[m].x); acc[m].y = fmaf(zv.y, w1.y, acc[m].y);
            acc[m].x = fmaf(zv.z, w2.x, acc[m].x); acc[m].y = fmaf(zv.z, w2.y, acc[m].y);
            acc[m].x = fmaf(zv.w, w3.x, acc[m].x); acc[m].y = fmaf(zv.w, w3.y, acc[m].y);
        }
    }
    #pragma unroll
    for (int m = 0; m < FTM; ++m) {
        h_lds[m][c0]     = gelu_f(acc[m].x);
        h_lds[m][c0 + 1] = gelu_f(acc[m].y);
    }
    __syncthreads();
    {
        const int j = tid & 31, mg = tid >> 5;
        float a0 = b2[j], a1 = a0;
        for (int c = 0; c < HH; c += 4) {
            float wa = W2[(size_t)(c + 0) * DDYN + j];
            float wb = W2[(size_t)(c + 1) * DDYN + j];
            float wc = W2[(size_t)(c + 2) * DDYN + j];
            float wd = W2[(size_t)(c + 3) * DDYN + j];
            float4 h0 = *(const float4*)&h_lds[mg][c];
            float4 h1 = *(const float4*)&h_lds[mg + 8][c];
            a0 = fmaf(h0.x, wa, a0); a0 = fmaf(h0.y, wb, a0);
            a0 = fmaf(h0.z, wc, a0); a0 = fmaf(h0.w, wd, a0);
            a1 = fmaf(h1.x, wa, a1); a1 = fmaf(h1.y, wb, a1);
            a1 = fmaf(h1.z, wc, a1); a1 = fmaf(h1.w, wd, a1);
        }
        fz_lds[mg][j] = a0; fz_lds[mg + 8][j] = a1;
    }
    __syncthreads();
    const size_t base = ((size_t)b * NN + n0) * (size_t)DDIM;
    for (int e = tid; e < nvalid * DDIM; e += 256) {
        int m = e / DDIM, d = e % DDIM;
        float v = xsrc[base + e];
        if (d < DDYN) v = fmaf(STEPSZ, fz_lds[m][d], v);
        xdst[base + e] = v;
    }
}

extern "C" void kernel_launch(void* const* d_in, const int* in_sizes, int n_in,
                              void* d_out, int out_size, void* d_ws, size_t ws_size,
                              hipStream_t stream) {
    const float* x   = (const float*)d_in[0];
    const int*   idx = (const int*)  d_in[1];
    const float* W1  = (const float*)d_in[2];
    const float* b1  = (const float*)d_in[3];
    const float* W2  = (const float*)d_in[4];
    const float* b2  = (const float*)d_in[5];
    float* out  = (float*)d_out;
    float* xbuf = (float*)d_ws;

    const size_t need = X_BYTES + (size_t)W1P_ELEMS * 2 + W2P_BYTES;
    if (ws_size >= need) {
        unsigned short* W1p = (unsigned short*)((char*)d_ws + X_BYTES);
        unsigned char*  W2p = (unsigned char*)(W1p + W1P_ELEMS);
        pack_w1<<<(W1P_ELEMS + 255) / 256, 256, 0, stream>>>(W1, W1p);
        pack_w2_fp8<<<(W2P_BYTES + 255) / 256, 256, 0, stream>>>(W2, W2p);
        dim3 grid((NN + TM - 1) / TM, BB), block(NTHR);
        step_mfma<<<grid, block, 0, stream>>>(x,    xbuf, idx, W1p, b1, W2p, b2);
        step_mfma<<<grid, block, 0, stream>>>(xbuf, out,  idx, W1p, b1, W2p, b2);
        step_mfma<<<grid, block, 0, stream>>>(out,  xbuf, idx, W1p, b1, W2p, b2);
        step_mfma<<<grid, block, 0, stream>>>(xbuf, out,  idx, W1p, b1, W2p, b2);
    } else {
        dim3 grid((NN + FTM - 1) / FTM, BB), block(256);
        step_f32<<<grid, block, 0, stream>>>(x,    xbuf, idx, W1, b1, W2, b2);
        step_f32<<<grid, block, 0, stream>>>(xbuf, out,  idx, W1, b1, W2, b2);
        step_f32<<<grid, block, 0, stream>>>(out,  xbuf, idx, W1, b1, W2, b2);
        step_f32<<<grid, block, 0, stream>>>(xbuf, out,  idx, W1, b1, W2, b2);
    }
}